// Round 1
// baseline (932.475 us; speedup 1.0000x reference)
//
#include <hip/hip_runtime.h>
#include <cstdint>

#define DI __device__ __forceinline__

// ---- problem constants (from setup_inputs: N=2e6, spatial=[480,360,32], scales=[2,4,1]) ----
constexpr int STRIDE_OUT = 18000001;   // per-scale output stride in int32 elements
constexpr int OFF_INV    = 8000000;
constexpr int OFF_COORS  = 10000000;
constexpr int OFF_NUM    = 18000000;

// dims per scale (loop order of scale_list = [2,4,1])
// scale=2: 240x180x16 ; scale=4: 120x90x8 ; scale=1: 480x360x32
// key space per scale = 8 * D0*D1*D2 (batches=8), all divisible by 32.
constexpr int RW0  = 0;         // word offset of scale-2 bitmap region
constexpr int RW1  = 172800;    // 8*240*180*16/32
constexpr int RW2  = 194400;    // + 8*120*90*8/32
constexpr int WTOT = 1576800;   // + 8*480*360*32/32
constexpr int NB1  = (WTOT + 1023) / 1024;  // scan blocks (1540)

// ---- strict (non-contractible) f32 ops so we bit-match XLA's mul,mul,add,sqrt ----
DI float fmul_s(float a, float b){ float r; asm("v_mul_f32 %0, %1, %2" : "=v"(r) : "v"(a), "v"(b)); return r; }
DI float fadd_s(float a, float b){ float r; asm("v_add_f32 %0, %1, %2" : "=v"(r) : "v"(a), "v"(b)); return r; }

DI void compute_keys(float x, float y, float z, int b, int (&key)[3], int (&g0)[3], int (&g1)[3], int (&g2)[3]) {
  const float PI_F     = 3.14159265358979323846f;  // -> 0x40490FDB (f32 pi, matches input array)
  const float TWO_PI_F = 6.28318530717958647692f;  // -> 0x40C90FDB == hi-lo exactly
  float rho = sqrtf(fadd_s(fmul_s(x, x), fmul_s(y, y)));
  float phi = atan2f(y, x);
  // t = (clip(v,lo,hi) - lo) / crop   (identical across scales, exactly as in reference)
  float tr = (fminf(fmaxf(rho, 0.0f), 50.0f) - 0.0f) / 50.0f;
  float tp = (fminf(fmaxf(phi, -PI_F), PI_F) + PI_F) / TWO_PI_F;
  float tz = (fminf(fmaxf(z, -4.0f), 2.0f) + 4.0f) / 6.0f;
  constexpr float C0[3] = {239.f, 119.f, 479.f};
  constexpr float C1[3] = {179.f,  89.f, 359.f};
  constexpr float C2[3] = { 15.f,   7.f,  31.f};
  constexpr int   D0[3] = {240, 120, 480};
  constexpr int   D1[3] = {180,  90, 360};
  constexpr int   D2[3] = { 16,   8,  32};
  #pragma unroll
  for (int s = 0; s < 3; ++s) {
    int a0 = (int)floorf(tr * C0[s]);
    int a1 = (int)floorf(tp * C1[s]);
    int a2 = (int)floorf(tz * C2[s]);
    g0[s] = a0; g1[s] = a1; g2[s] = a2;
    key[s] = ((b * D0[s] + a0) * D1[s] + a1) * D2[s] + a2;
  }
}

// ---- pass B: per point -> bxyz out + presence bits ----
__global__ __launch_bounds__(256) void pass_points(const float4* __restrict__ pts,
                                                   const int* __restrict__ batch,
                                                   int n, uint32_t* __restrict__ bitmap,
                                                   int* __restrict__ out) {
  int i = blockIdx.x * 256 + threadIdx.x;
  if (i >= n) return;
  float4 p = pts[i];
  int b = batch[i];
  int key[3], g0[3], g1[3], g2[3];
  compute_keys(p.x, p.y, p.z, b, key, g0, g1, g2);
  constexpr int RW[3] = {RW0, RW1, RW2};
  #pragma unroll
  for (int s = 0; s < 3; ++s) {
    int* o = out + s * STRIDE_OUT + i * 4;
    o[0] = b; o[1] = g0[s]; o[2] = g1[s]; o[3] = g2[s];
    atomicOr(&bitmap[RW[s] + (key[s] >> 5)], 1u << (key[s] & 31));
  }
}

// ---- scan step 1: per-block popcount sums (1024 words/block) ----
__global__ __launch_bounds__(256) void scan1(const uint32_t* __restrict__ bitmap,
                                             uint32_t* __restrict__ blockSums) {
  __shared__ uint32_t lds[256];
  int t = threadIdx.x;
  int base = blockIdx.x * 1024 + t * 4;
  uint32_t s = 0;
  if (base + 4 <= WTOT) {
    uint4 w = *reinterpret_cast<const uint4*>(bitmap + base);
    s = __popc(w.x) + __popc(w.y) + __popc(w.z) + __popc(w.w);
  } else {
    for (int k = 0; k < 4; ++k) if (base + k < WTOT) s += __popc(bitmap[base + k]);
  }
  lds[t] = s; __syncthreads();
  for (int off = 128; off > 0; off >>= 1) { if (t < off) lds[t] += lds[t + off]; __syncthreads(); }
  if (t == 0) blockSums[blockIdx.x] = lds[0];
}

// ---- scan step 2: exclusive scan of block sums (single block), writes grand total ----
__global__ __launch_bounds__(256) void scan2(uint32_t* __restrict__ blockSums,
                                             uint32_t* __restrict__ prefix, int nb) {
  __shared__ uint32_t lds[256];
  int t = threadIdx.x;
  uint32_t local[7]; uint32_t sum = 0;
  #pragma unroll
  for (int k = 0; k < 7; ++k) { int idx = t * 7 + k; uint32_t v = (idx < nb) ? blockSums[idx] : 0u; local[k] = v; sum += v; }
  lds[t] = sum; __syncthreads();
  for (int off = 1; off < 256; off <<= 1) {
    uint32_t x = (t >= off) ? lds[t - off] : 0u; __syncthreads();
    lds[t] += x; __syncthreads();
  }
  uint32_t run = lds[t] - sum;  // exclusive
  #pragma unroll
  for (int k = 0; k < 7; ++k) { int idx = t * 7 + k; if (idx < nb) blockSums[idx] = run; run += local[k]; }
  if (t == 255) prefix[WTOT] = run;  // grand total bits
}

// ---- scan step 3: per-word exclusive prefix ----
__global__ __launch_bounds__(256) void scan3(const uint32_t* __restrict__ bitmap,
                                             const uint32_t* __restrict__ blockSums,
                                             uint32_t* __restrict__ prefix) {
  __shared__ uint32_t lds[256];
  int t = threadIdx.x;
  int base = blockIdx.x * 1024 + t * 4;
  uint32_t c[4]; uint32_t sum = 0;
  if (base + 4 <= WTOT) {
    uint4 w = *reinterpret_cast<const uint4*>(bitmap + base);
    c[0] = __popc(w.x); c[1] = __popc(w.y); c[2] = __popc(w.z); c[3] = __popc(w.w);
  } else {
    #pragma unroll
    for (int k = 0; k < 4; ++k) c[k] = (base + k < WTOT) ? __popc(bitmap[base + k]) : 0u;
  }
  sum = c[0] + c[1] + c[2] + c[3];
  lds[t] = sum; __syncthreads();
  for (int off = 1; off < 256; off <<= 1) {
    uint32_t x = (t >= off) ? lds[t - off] : 0u; __syncthreads();
    lds[t] += x; __syncthreads();
  }
  uint32_t excl = lds[t] - sum + blockSums[blockIdx.x];
  #pragma unroll
  for (int k = 0; k < 4; ++k) { if (base + k < WTOT) prefix[base + k] = excl; excl += c[k]; }
}

// ---- pass C: per point -> inv (rank) ----
__global__ __launch_bounds__(256) void pass_inv(const float4* __restrict__ pts,
                                                const int* __restrict__ batch, int n,
                                                const uint32_t* __restrict__ bitmap,
                                                const uint32_t* __restrict__ prefix,
                                                int* __restrict__ out) {
  int i = blockIdx.x * 256 + threadIdx.x;
  if (i >= n) return;
  float4 p = pts[i];
  int b = batch[i];
  int key[3], g0[3], g1[3], g2[3];
  compute_keys(p.x, p.y, p.z, b, key, g0, g1, g2);
  constexpr int RW[3] = {RW0, RW1, RW2};
  #pragma unroll
  for (int s = 0; s < 3; ++s) {
    int w = RW[s] + (key[s] >> 5);
    uint32_t bits = bitmap[w];
    uint32_t base = prefix[w] - prefix[RW[s]];
    int rank = (int)(base + __popc(bits & ((1u << (key[s] & 31)) - 1u)));
    out[s * STRIDE_OUT + OFF_INV + i] = rank;
  }
}

// ---- pass D: per bitmap word -> coors rows in rank order ----
template <int S>
__global__ __launch_bounds__(256) void pass_coors(const uint32_t* __restrict__ bitmap,
                                                  const uint32_t* __restrict__ prefix,
                                                  int* __restrict__ out) {
  constexpr int RW[3] = {RW0, RW1, RW2};
  constexpr int NW[3] = {RW1 - RW0, RW2 - RW1, WTOT - RW2};
  constexpr int D0[3] = {240, 120, 480};
  constexpr int D1[3] = {180,  90, 360};
  constexpr int D2[3] = { 16,   8,  32};
  int wi = blockIdx.x * 256 + threadIdx.x;
  if (wi >= NW[S]) return;
  int w = RW[S] + wi;
  uint32_t bits = bitmap[w];
  if (!bits) return;
  uint32_t rank = prefix[w] - prefix[RW[S]];
  int keybase = wi * 32;
  int* coors = out + S * STRIDE_OUT + OFF_COORS;
  while (bits) {
    int j = __builtin_ctz(bits);
    bits &= bits - 1;
    int key = keybase + j;
    int gz = key & (D2[S] - 1);
    int r  = key / D2[S];              // pow2 shift
    int q  = r / D1[S];                // magic mul (constant)
    int gy = r - q * D1[S];
    int bq = q / D0[S];
    int gx = q - bq * D0[S];
    int* o = coors + (int)rank * 4;
    o[0] = bq; o[1] = gz; o[2] = gy; o[3] = gx;   // coors = [b, z, phi, rho]
    ++rank;
  }
}

// ---- pass E: zero coors tail, write num ----
__global__ __launch_bounds__(256) void pass_tail(const uint32_t* __restrict__ prefix,
                                                 int* __restrict__ out, int n) {
  int s = blockIdx.y;
  int rs  = (s == 0) ? RW0 : (s == 1) ? RW1 : RW2;
  int re  = (s == 0) ? RW1 : (s == 1) ? RW2 : WTOT;
  uint32_t num = prefix[re] - prefix[rs];
  int i = blockIdx.x * 256 + threadIdx.x;
  if (i == 0) out[s * STRIDE_OUT + OFF_NUM] = (int)num;
  if (i >= (int)num && i < n) {
    int* o = out + s * STRIDE_OUT + OFF_COORS + i * 4;
    o[0] = 0; o[1] = 0; o[2] = 0; o[3] = 0;
  }
}

extern "C" void kernel_launch(void* const* d_in, const int* in_sizes, int n_in,
                              void* d_out, int out_size, void* d_ws, size_t ws_size,
                              hipStream_t stream) {
  const float4* pts  = (const float4*)d_in[0];
  const int*    batch = (const int*)d_in[1];
  int n = in_sizes[1];  // 2,000,000
  int* out = (int*)d_out;

  uint32_t* bitmap    = (uint32_t*)d_ws;            // WTOT words
  uint32_t* prefix    = bitmap + WTOT;              // WTOT+1 words
  uint32_t* blockSums = prefix + WTOT + 1;          // NB1 words
  // total ws use: ~12.6 MB

  hipMemsetAsync(bitmap, 0, (size_t)WTOT * sizeof(uint32_t), stream);

  int nblk = (n + 255) / 256;
  pass_points<<<nblk, 256, 0, stream>>>(pts, batch, n, bitmap, out);
  scan1<<<NB1, 256, 0, stream>>>(bitmap, blockSums);
  scan2<<<1, 256, 0, stream>>>(blockSums, prefix, NB1);
  scan3<<<NB1, 256, 0, stream>>>(bitmap, blockSums, prefix);
  pass_inv<<<nblk, 256, 0, stream>>>(pts, batch, n, bitmap, prefix, out);
  pass_coors<0><<<(RW1 - RW0 + 255) / 256, 256, 0, stream>>>(bitmap, prefix, out);
  pass_coors<1><<<(RW2 - RW1 + 255) / 256, 256, 0, stream>>>(bitmap, prefix, out);
  pass_coors<2><<<(WTOT - RW2 + 255) / 256, 256, 0, stream>>>(bitmap, prefix, out);
  dim3 gtail((unsigned)nblk, 3);
  pass_tail<<<gtail, 256, 0, stream>>>(prefix, out, n);
}